// Round 7
// baseline (220.596 us; speedup 1.0000x reference)
//
#include <hip/hip_runtime.h>
#include <hip/hip_cooperative_groups.h>

namespace cg = cooperative_groups;

typedef unsigned short u16;
typedef unsigned int   u32;
typedef _Float16 h2  __attribute__((ext_vector_type(2)));   // arithmetic type
typedef __fp16   hw2 __attribute__((ext_vector_type(2)));   // builtin boundary
typedef __fp16   hw8 __attribute__((ext_vector_type(8)));   // mfma operand
typedef float    f4  __attribute__((ext_vector_type(4)));   // mfma accumulator

// LDS row stride for sX / sXl in u16 elements: 136*2 = 272 B -> row starts 16B-aligned.
#define XS 136

static __device__ __forceinline__ h2 pk(float a, float b) {
    return __builtin_bit_cast(h2, __builtin_amdgcn_cvt_pkrtz(a, b));
}
static __device__ __forceinline__ float dot2(h2 a, h2 b, float c) {
    return __builtin_amdgcn_fdot2(__builtin_bit_cast(hw2, a),
                                  __builtin_bit_cast(hw2, b), c, false);   // v_dot2_f32_f16
}
static __device__ __forceinline__ h2  b2h(u32 v) { return __builtin_bit_cast(h2, v); }
static __device__ __forceinline__ u32 h2u(h2 v)  { return __builtin_bit_cast(u32, v); }
static __device__ __forceinline__ h2  abs2(h2 v) { return b2h(h2u(v) & 0x7fff7fffu); }
static __device__ __forceinline__ u16 f2h(float f) { return __builtin_bit_cast(u16, (_Float16)f); }
static __device__ __forceinline__ float h2f(u16 v) { return (float)__builtin_bit_cast(_Float16, v); }
static __device__ __forceinline__ f4 mfma16(uint4 a, uint4 b, f4 c) {
    return __builtin_amdgcn_mfma_f32_16x16x32_f16(__builtin_bit_cast(hw8, a),
                                                  __builtin_bit_cast(hw8, b), c, 0, 0, 0);
}
static __device__ __forceinline__ h2 shflx32(h2 v) {
    return b2h((u32)__shfl_xor((int)h2u(v), 32));
}

// ---------------- K0: pack weights f32 -> MFMA B-fragment-ordered f16 ----------------
// wpk (u32): [0]=L1 [8192]=R1 [16384]=L2 [24576]=R2 [32768]=L3 [36864]=R3 ; 160 KB
__global__ void pack_weights(const float* __restrict__ Wl1, const float* __restrict__ Wr1,
                             const float* __restrict__ Wl2, const float* __restrict__ Wr2,
                             const float* __restrict__ Wl3, const float* __restrict__ Wr3,
                             u32* __restrict__ wpk)
{
    const int o = blockIdx.x * 256 + threadIdx.x;    // 0 .. 40959
    const float* src; u32* dst; int local; int N;
    if      (o < 8192)  { src = Wl1; dst = wpk;         local = o;         N = 128; }
    else if (o < 16384) { src = Wr1; dst = wpk + 8192;  local = o - 8192;  N = 128; }
    else if (o < 24576) { src = Wl2; dst = wpk + 16384; local = o - 16384; N = 128; }
    else if (o < 32768) { src = Wr2; dst = wpk + 24576; local = o - 24576; N = 128; }
    else if (o < 36864) { src = Wl3; dst = wpk + 32768; local = o - 32768; N = 64;  }
    else                { src = Wr3; dst = wpk + 36864; local = o - 36864; N = 64;  }
    const int i2   = local & 3;
    const int lane = (local >> 2) & 63;
    const int frag = local >> 8;
    const int kb   = frag & 3;
    const int nt   = frag >> 2;
    const int k0   = kb*32 + ((lane >> 4) << 3) + i2*2;
    const int n    = nt*16 + (lane & 15);
    dst[local] = h2u(pk(src[k0*N + n], src[(k0+1)*N + n]));
}

// full 128-col MFMA projection: sX (64x128 f16) -> sXl [m][n], sXrP packed [c8][node]x8
static __device__ __forceinline__ void matmul128(int w, int lane,
    const u32* __restrict__ wpkL, const u32* __restrict__ wpkR,
    const u16* sX, u16* sXl, uint4* sXrP)
{
    const int  mt  = w & 3;
    const bool isR = (w >= 4);
    const u32* wp  = isR ? wpkR : wpkL;
    const int  n15 = lane & 15;
    const int  qd  = lane >> 4;
    uint4 afr[4];
#pragma unroll
    for (int kb = 0; kb < 4; kb++)
        afr[kb] = *(const uint4*)&sX[(mt*16 + n15)*XS + kb*32 + (qd << 3)];
#pragma unroll
    for (int nt = 0; nt < 8; nt++) {
        f4 acc = {0.f, 0.f, 0.f, 0.f};
#pragma unroll
        for (int kb = 0; kb < 4; kb++) {
            uint4 bf = *(const uint4*)&wp[((nt*4 + kb)*64 + lane)*4];
            acc = mfma16(afr[kb], bf, acc);
        }
        const int n  = nt*16 + n15;
        const int mb = mt*16 + (qd << 2);
        if (!isR) {
#pragma unroll
            for (int r = 0; r < 4; r++) sXl[(mb + r)*XS + n] = f2h(acc[r]);
        } else {
            u16* xp = (u16*)sXrP;
#pragma unroll
            for (int r = 0; r < 4; r++)
                xp[(((n >> 3)*64) + mb + r)*8 + (n & 7)] = f2h(acc[r]);
        }
    }
}

// attention (H=4,C=32) + bias + LN + ReLU for this block's 32 dst nodes; writes f16 x to gxOut
static __device__ __forceinline__ void attn_ln(int t, int w, int lane, int b, int jh,
    const float* __restrict__ att, const float* __restrict__ bias,
    const float* __restrict__ lg, const float* __restrict__ lb,
    u16* sX, const u16* sXl, const uint4* sXrP,
    float* sAl, float* sPart, float* sL2, const float* sImp, u32* __restrict__ gxOut)
{
    const int h  = w & 3;
    const int ih = w >> 2;
    const int jj = lane & 31;
    const int is = lane >> 5;
    const int j  = jh*32 + jj;

    h2 a2[16];
#pragma unroll
    for (int q = 0; q < 16; q++) a2[q] = pk(att[h*32 + 2*q], att[h*32 + 2*q + 1]);

    // Al[h][i] for all 64 i — waves 0-3, i = lane
    if (w < 4) {
        const uint4* pr = (const uint4*)&sXl[lane*XS + h*32];
        float al = 0.f;
#pragma unroll
        for (int c4 = 0; c4 < 4; c4++) {
            uint4 v = pr[c4];
            al = dot2(b2h(v.x), a2[c4*4+0], al);
            al = dot2(b2h(v.y), a2[c4*4+1], al);
            al = dot2(b2h(v.z), a2[c4*4+2], al);
            al = dot2(b2h(v.w), a2[c4*4+3], al);
        }
        sAl[h*64 + lane] = al;
    }

    // xr_j from packed buffer
    h2 xr2[16];
#pragma unroll
    for (int s = 0; s < 4; s++) {
        uint4 v = sXrP[(h*4 + s)*64 + j];
        xr2[s*4+0] = b2h(v.x); xr2[s*4+1] = b2h(v.y);
        xr2[s*4+2] = b2h(v.z); xr2[s*4+3] = b2h(v.w);
    }
    float Ar = 0.f;
#pragma unroll
    for (int q = 0; q < 16; q++) Ar = dot2(a2[q], xr2[q], Ar);
    const float impj = sImp[j];
    __syncthreads();            // sAl ready

    // i-loop: 16 i's per thread (ih cross-wave split x is in-wave split)
    float l = 0.f;
    h2 acc2[16];
#pragma unroll
    for (int q = 0; q < 16; q++) acc2[q] = b2h(0u);
    const int i0 = ih*32 + is*16;
#pragma unroll 4
    for (int ii = 0; ii < 16; ii++) {
        int i = i0 + ii;
        const uint4* pl = (const uint4*)&sXl[i*XS + h*32];
        uint4 v0 = pl[0], v1 = pl[1], v2 = pl[2], v3 = pl[3];
        h2 xl2[16];
        xl2[0] = b2h(v0.x); xl2[1] = b2h(v0.y); xl2[2]  = b2h(v0.z); xl2[3]  = b2h(v0.w);
        xl2[4] = b2h(v1.x); xl2[5] = b2h(v1.y); xl2[6]  = b2h(v1.z); xl2[7]  = b2h(v1.w);
        xl2[8] = b2h(v2.x); xl2[9] = b2h(v2.y); xl2[10] = b2h(v2.z); xl2[11] = b2h(v2.w);
        xl2[12]= b2h(v3.x); xl2[13]= b2h(v3.y); xl2[14] = b2h(v3.z); xl2[15] = b2h(v3.w);
        float S0 = 0.f, S1 = 0.f;
#pragma unroll
        for (int q = 0; q < 16; q += 2) {
            h2 t0 = abs2(xl2[q]   + xr2[q]);
            h2 t1 = abs2(xl2[q+1] + xr2[q+1]);
            S0 = dot2(a2[q],   t0, S0);
            S1 = dot2(a2[q+1], t1, S1);
        }
        float e  = 0.6f*(sAl[h*64 + i] + Ar) + 0.4f*(S0 + S1);
        float ad = (i == j) ? 1.f : impj * sImp[i];
        float p  = (ad != 0.f) ? __expf(e) : 0.f;
        l += p;
        h2 p2 = pk(p, p);
#pragma unroll
        for (int q = 0; q < 16; q++) acc2[q] += p2 * xl2[q];
    }

    // in-wave combine (is halves)
    l += __shfl_xor(l, 32);
#pragma unroll
    for (int q = 0; q < 16; q++) acc2[q] = acc2[q] + shflx32(acc2[q]);

    // cross-wave (ih) combine via overlay on sX (x dead now); row stride 20 u32 (16B-aligned)
    u32* ov = (u32*)sX;
    if (w >= 4 && lane < 32) {
        uint4* d4 = (uint4*)(ov + (h*32 + jj)*20);
        uint4 o;
        o.x = h2u(acc2[0]);  o.y = h2u(acc2[1]);  o.z = h2u(acc2[2]);  o.w = h2u(acc2[3]);  d4[0] = o;
        o.x = h2u(acc2[4]);  o.y = h2u(acc2[5]);  o.z = h2u(acc2[6]);  o.w = h2u(acc2[7]);  d4[1] = o;
        o.x = h2u(acc2[8]);  o.y = h2u(acc2[9]);  o.z = h2u(acc2[10]); o.w = h2u(acc2[11]); d4[2] = o;
        o.x = h2u(acc2[12]); o.y = h2u(acc2[13]); o.z = h2u(acc2[14]); o.w = h2u(acc2[15]); d4[3] = o;
        sL2[h*32 + jj] = l;
    }
    __syncthreads();

    float yv[32];
    if (w < 4 && lane < 32) {
        const uint4* s4 = (const uint4*)(ov + (h*32 + jj)*20);
        uint4 u0 = s4[0], u1 = s4[1], u2 = s4[2], u3 = s4[3];
        h2 oth[16];
        oth[0] = b2h(u0.x); oth[1] = b2h(u0.y); oth[2]  = b2h(u0.z); oth[3]  = b2h(u0.w);
        oth[4] = b2h(u1.x); oth[5] = b2h(u1.y); oth[6]  = b2h(u1.z); oth[7]  = b2h(u1.w);
        oth[8] = b2h(u2.x); oth[9] = b2h(u2.y); oth[10] = b2h(u2.z); oth[11] = b2h(u2.w);
        oth[12]= b2h(u3.x); oth[13]= b2h(u3.y); oth[14] = b2h(u3.z); oth[15] = b2h(u3.w);
        l += sL2[h*32 + jj];
        const float rl = 1.f / l;
        float s1 = 0.f, s2v = 0.f;
#pragma unroll
        for (int q = 0; q < 16; q++) {
            h2 sum = acc2[q] + oth[q];
            float y0 = fmaf((float)sum[0], rl, bias[h*32 + 2*q]);
            float y1 = fmaf((float)sum[1], rl, bias[h*32 + 2*q + 1]);
            yv[2*q] = y0; yv[2*q+1] = y1;
            s1 += y0 + y1;
            s2v = fmaf(y0, y0, s2v);
            s2v = fmaf(y1, y1, s2v);
        }
        sPart[h*32 + jj]       = s1;
        sPart[128 + h*32 + jj] = s2v;
    }
    __syncthreads();

    if (w < 4 && lane < 32) {
        float su = sPart[jj] + sPart[32 + jj] + sPart[64 + jj] + sPart[96 + jj];
        float sq = sPart[128 + jj] + sPart[160 + jj] + sPart[192 + jj] + sPart[224 + jj];
        const float mean = su * 0.0078125f;
        const float var  = sq * 0.0078125f - mean*mean;
        const float rstd = rsqrtf(var + 1e-5f);
#pragma unroll
        for (int q = 0; q < 16; q++) {
            int f0 = h*32 + 2*q;
            float v0 = fmaxf(fmaf((yv[2*q]   - mean)*rstd, lg[f0],   lb[f0]),   0.f);
            float v1 = fmaxf(fmaf((yv[2*q+1] - mean)*rstd, lg[f0+1], lb[f0+1]), 0.f);
            ov[(h*32 + jj)*20 + q] = h2u(pk(v0, v1));
        }
    }
    __syncthreads();

    // coalesced store of this block's 32 nodes (f16-pair u32) to global
    for (int r = t; r < 2048; r += 512) {
        int nj = r >> 6, c = r & 63, hh = c >> 4, qq = c & 15;
        gxOut[(size_t)b*4096 + (size_t)(jh*32 + nj)*64 + c] = ov[(hh*32 + nj)*20 + qq];
    }
}

// ---------------- cooperative mono-kernel: embed + 3 GAT layers ----------------
__global__ void __launch_bounds__(512) gnn_all(
    const float* __restrict__ team_obs, const float* __restrict__ target_obs,
    const float* __restrict__ team_mask, const float* __restrict__ ltm,
    const float* __restrict__ W_emb, const float* __restrict__ b_emb,
    const float* __restrict__ att1, const float* __restrict__ b1,
    const float* __restrict__ att2, const float* __restrict__ b2,
    const float* __restrict__ att3, const float* __restrict__ b3,
    const float* __restrict__ ln1_g, const float* __restrict__ ln1_b,
    const float* __restrict__ ln2_g, const float* __restrict__ ln2_b,
    const u32* __restrict__ wpk, u32* __restrict__ gx1, u32* __restrict__ gx2,
    float* __restrict__ out)
{
    __shared__ __align__(16) u16   sX  [64*XS];   // 17408 B; overlays: acc-combine
    __shared__ __align__(16) u16   sXl [64*XS];   // 17408 B
    __shared__ __align__(16) uint4 sXrP[1024];    // 16384 B
    __shared__ __align__(16) float sFin[1024];    //  4096 B; layer-3 sE overlays
    __shared__ float sAl [256];                   //  1024 B
    __shared__ float sPart[512];                  //  2048 B
    __shared__ float sL2 [128];                   //   512 B
    __shared__ float sImp[64];                    //   256 B
    // total 59136 B

    cg::grid_group grid = cg::this_grid();

    const int t    = threadIdx.x;
    const int w    = t >> 6;
    const int lane = t & 63;
    const int b    = blockIdx.x >> 1;
    const int jh   = blockIdx.x & 1;

    // ---------------- masks + assembled input features ----------------
    if (t < 64) {
        float im;
        if (t < 16) im = (team_mask[b*32 + t] != -1000000000.0f) ? 1.f : 0.f;
        else        im = (ltm[b*49 + (t-16)] != 0.0f) ? 1.f : 0.f;
        sImp[t] = im;
    }
    for (int ee = t; ee < 1024; ee += 512) {
        int m = ee >> 4, k = ee & 15;
        float v = 0.f;
        if (m < 16) {
            if (k < 14) v = team_obs[(b*16 + m)*14 + k];
        } else {
            const float* tg = target_obs + (size_t)(b*48 + (m-16))*15;
            if      (k < 12)  v = tg[k];
            else if (k == 14) v = tg[12];
            else if (k == 15) v = tg[13];
        }
        sFin[m*16 + k] = v;
    }
    __syncthreads();

    // ---------------- embed: x = fin @ W_emb + b_emb -> sX (f16) ----------------
    {
        const int f = t & 127;
        const int g = t >> 7;
        float wreg[16];
#pragma unroll
        for (int k = 0; k < 16; k++) wreg[k] = W_emb[k*128 + f];
        const float bf = b_emb[f];
#pragma unroll
        for (int mm = 0; mm < 16; mm++) {
            int m = g*16 + mm;
            const float4* pf = (const float4*)&sFin[m*16];
            float4 f0 = pf[0], f1 = pf[1], f2 = pf[2], f3 = pf[3];
            float acc = bf;
            acc = fmaf(f0.x, wreg[0],  acc); acc = fmaf(f0.y, wreg[1],  acc);
            acc = fmaf(f0.z, wreg[2],  acc); acc = fmaf(f0.w, wreg[3],  acc);
            acc = fmaf(f1.x, wreg[4],  acc); acc = fmaf(f1.y, wreg[5],  acc);
            acc = fmaf(f1.z, wreg[6],  acc); acc = fmaf(f1.w, wreg[7],  acc);
            acc = fmaf(f2.x, wreg[8],  acc); acc = fmaf(f2.y, wreg[9],  acc);
            acc = fmaf(f2.z, wreg[10], acc); acc = fmaf(f2.w, wreg[11], acc);
            acc = fmaf(f3.x, wreg[12], acc); acc = fmaf(f3.y, wreg[13], acc);
            acc = fmaf(f3.z, wreg[14], acc); acc = fmaf(f3.w, wreg[15], acc);
            sX[m*XS + f] = f2h(acc);
        }
    }
    __syncthreads();

    // ---------------- layer 1 ----------------
    matmul128(w, lane, wpk, wpk + 8192, sX, sXl, sXrP);
    __syncthreads();
    attn_ln(t, w, lane, b, jh, att1, b1, ln1_g, ln1_b,
            sX, sXl, sXrP, sAl, sPart, sL2, sImp, gx1);
    grid.sync();

    // ---------------- layer 2 ----------------
    {
        const uint4* gin = (const uint4*)(gx1 + (size_t)b*4096);
        for (int r = t; r < 1024; r += 512) {
            uint4 v = gin[r];
            int m = r >> 4, seg = r & 15;
            *(uint4*)&sX[m*XS + seg*8] = v;
        }
    }
    __syncthreads();
    matmul128(w, lane, wpk + 16384, wpk + 24576, sX, sXl, sXrP);
    __syncthreads();
    attn_ln(t, w, lane, b, jh, att2, b2, ln2_g, ln2_b,
            sX, sXl, sXrP, sAl, sPart, sL2, sImp, gx2);
    grid.sync();

    // ---------------- layer 3 (H=1, C=64) ----------------
    {
        const uint4* gin = (const uint4*)(gx2 + (size_t)b*4096);
        for (int r = t; r < 1024; r += 512) {
            uint4 v = gin[r];
            int m = r >> 4, seg = r & 15;
            *(uint4*)&sX[m*XS + seg*8] = v;
        }
    }
    __syncthreads();

    // layer-3 MFMA matmul (HC = 64)
    {
        const int  mt  = w & 3;
        const bool isR = (w >= 4);
        const u32* wp  = isR ? (wpk + 36864) : (wpk + 32768);
        const int  n15 = lane & 15;
        const int  qd  = lane >> 4;
        uint4 afr[4];
#pragma unroll
        for (int kb = 0; kb < 4; kb++)
            afr[kb] = *(const uint4*)&sX[(mt*16 + n15)*XS + kb*32 + (qd << 3)];
#pragma unroll
        for (int nt = 0; nt < 4; nt++) {
            f4 acc = {0.f, 0.f, 0.f, 0.f};
#pragma unroll
            for (int kb = 0; kb < 4; kb++) {
                uint4 bf = *(const uint4*)&wp[((nt*4 + kb)*64 + lane)*4];
                acc = mfma16(afr[kb], bf, acc);
            }
            const int n  = nt*16 + n15;
            const int mb = mt*16 + (qd << 2);
            if (!isR) {
#pragma unroll
                for (int r = 0; r < 4; r++) sXl[(mb + r)*XS + n] = f2h(acc[r]);
            } else {
                u16* xp = (u16*)sXrP;
#pragma unroll
                for (int r = 0; r < 4; r++)
                    xp[(((n >> 3)*64) + mb + r)*8 + (n & 7)] = f2h(acc[r]);
            }
        }
    }
    __syncthreads();

    // Al3[i] (8-way c-split)
    {
        h2 a2l[4];
#pragma unroll
        for (int q = 0; q < 4; q++) a2l[q] = pk(att3[w*8 + 2*q], att3[w*8 + 2*q + 1]);
        uint4 v = *(const uint4*)&sXl[lane*XS + w*8];
        float al = 0.f;
        al = dot2(b2h(v.x), a2l[0], al);
        al = dot2(b2h(v.y), a2l[1], al);
        al = dot2(b2h(v.z), a2l[2], al);
        al = dot2(b2h(v.w), a2l[3], al);
        sPart[w*64 + lane] = al;
    }
    __syncthreads();
    if (t < 64) {
        sAl[t] = ((sPart[t] + sPart[64+t]) + (sPart[128+t] + sPart[192+t]))
               + ((sPart[256+t] + sPart[320+t]) + (sPart[384+t] + sPart[448+t]));
    }
    __syncthreads();

    {
        const int jj = lane & 31;
        const int is = lane >> 5;
        const int j  = jh*32 + jj;
        u16* sE = (u16*)sFin;           // 4096 B overlay (sFin dead)

        // scores e[i][jj]; i split 16 ways (8 waves x 2 in-wave)
        {
            h2 a3[32], xr3[32];
#pragma unroll
            for (int q = 0; q < 32; q++) a3[q] = pk(att3[2*q], att3[2*q + 1]);
#pragma unroll
            for (int s = 0; s < 8; s++) {
                uint4 v = sXrP[s*64 + j];
                xr3[s*4+0] = b2h(v.x); xr3[s*4+1] = b2h(v.y);
                xr3[s*4+2] = b2h(v.z); xr3[s*4+3] = b2h(v.w);
            }
            float Ar = 0.f;
#pragma unroll
            for (int q = 0; q < 32; q++) Ar = dot2(a3[q], xr3[q], Ar);
            const float impj = sImp[j];
            const int ib = (w*2 + is)*4;
            for (int ii = 0; ii < 4; ii++) {
                int i = ib + ii;
                const uint4* pl = (const uint4*)&sXl[i*XS];
                float S0 = 0.f, S1 = 0.f;
#pragma unroll
                for (int c4 = 0; c4 < 8; c4++) {
                    uint4 v = pl[c4];
                    S0 = dot2(a3[c4*4+0], abs2(b2h(v.x) + xr3[c4*4+0]), S0);
                    S1 = dot2(a3[c4*4+1], abs2(b2h(v.y) + xr3[c4*4+1]), S1);
                    S0 = dot2(a3[c4*4+2], abs2(b2h(v.z) + xr3[c4*4+2]), S0);
                    S1 = dot2(a3[c4*4+3], abs2(b2h(v.w) + xr3[c4*4+3]), S1);
                }
                float e  = 0.6f*(sAl[i] + Ar) + 0.4f*(S0 + S1);
                float ad = (i == j) ? 1.f : impj * sImp[i];
                e = (ad != 0.f) ? e : -60000.0f;
                sE[i*32 + jj] = f2h(e);
            }
        }
        __syncthreads();

        // softmax + aggregate (c split 8 ways, i split 2 in-wave)
        {
            const int c0 = w*8;
            h2 acc2[4];
#pragma unroll
            for (int q = 0; q < 4; q++) acc2[q] = b2h(0u);
            float l = 0.f;
            for (int k = 0; k < 32; k++) {
                int i = is*32 + k;
                float p = __expf(h2f(sE[i*32 + jj]));
                l += p;
                h2 p2 = pk(p, p);
                uint4 v = *(const uint4*)&sXl[i*XS + c0];
                acc2[0] += p2 * b2h(v.x);
                acc2[1] += p2 * b2h(v.y);
                acc2[2] += p2 * b2h(v.z);
                acc2[3] += p2 * b2h(v.w);
            }
            l += __shfl_xor(l, 32);
#pragma unroll
            for (int q = 0; q < 4; q++) acc2[q] = acc2[q] + shflx32(acc2[q]);
            if (is == 0) {
                const float rl = 1.f / l;
                float o[8];
#pragma unroll
                for (int q = 0; q < 4; q++) {
                    o[2*q]   = fmaf((float)acc2[q][0], rl, b3[c0 + 2*q]);
                    o[2*q+1] = fmaf((float)acc2[q][1], rl, b3[c0 + 2*q + 1]);
                }
                float4* po = (float4*)(out + (size_t)b*4096 + (size_t)j*64 + c0);
                po[0] = *(const float4*)&o[0];
                po[1] = *(const float4*)&o[4];
            }
        }
    }
}

extern "C" void kernel_launch(void* const* d_in, const int* in_sizes, int n_in,
                              void* d_out, int out_size, void* d_ws, size_t ws_size,
                              hipStream_t stream) {
    (void)in_sizes; (void)n_in; (void)ws_size; (void)out_size;
    const float* team_obs          = (const float*)d_in[0];
    const float* target_obs        = (const float*)d_in[1];
    const float* team_mask         = (const float*)d_in[2];
    const float* local_target_mask = (const float*)d_in[3];
    const float* W_emb             = (const float*)d_in[4];
    const float* b_emb             = (const float*)d_in[5];
    const float* Wl1               = (const float*)d_in[6];
    const float* Wr1               = (const float*)d_in[7];
    const float* att1              = (const float*)d_in[8];
    const float* b1                = (const float*)d_in[9];
    const float* Wl2               = (const float*)d_in[10];
    const float* Wr2               = (const float*)d_in[11];
    const float* att2              = (const float*)d_in[12];
    const float* b2                = (const float*)d_in[13];
    const float* Wl3               = (const float*)d_in[14];
    const float* Wr3               = (const float*)d_in[15];
    const float* att3              = (const float*)d_in[16];
    const float* b3                = (const float*)d_in[17];
    const float* ln1_g             = (const float*)d_in[18];
    const float* ln1_b             = (const float*)d_in[19];
    const float* ln2_g             = (const float*)d_in[20];
    const float* ln2_b             = (const float*)d_in[21];
    float* out = (float*)d_out;

    u32* wpk = (u32*)d_ws;                 // 163840 B
    u32* gx1 = (u32*)d_ws + 40960;         // 2 MB layer-1 activations
    u32* gx2 = (u32*)d_ws + 40960 + 524288;// 2 MB layer-2 activations

    pack_weights<<<dim3(160), dim3(256), 0, stream>>>(Wl1, Wr1, Wl2, Wr2, Wl3, Wr3, wpk);

    void* args[] = {
        (void*)&team_obs, (void*)&target_obs, (void*)&team_mask, (void*)&local_target_mask,
        (void*)&W_emb, (void*)&b_emb,
        (void*)&att1, (void*)&b1, (void*)&att2, (void*)&b2, (void*)&att3, (void*)&b3,
        (void*)&ln1_g, (void*)&ln1_b, (void*)&ln2_g, (void*)&ln2_b,
        (void*)&wpk, (void*)&gx1, (void*)&gx2, (void*)&out
    };
    hipLaunchCooperativeKernel((void*)gnn_all, dim3(256), dim3(512), args, 0, stream);
}

// Round 8
// 137.750 us; speedup vs baseline: 1.6014x; 1.6014x over previous
//
#include <hip/hip_runtime.h>

typedef unsigned short u16;
typedef unsigned int   u32;
typedef _Float16 h2  __attribute__((ext_vector_type(2)));   // arithmetic type
typedef __fp16   hw2 __attribute__((ext_vector_type(2)));   // builtin boundary
typedef __fp16   hw8 __attribute__((ext_vector_type(8)));   // mfma operand
typedef float    f4  __attribute__((ext_vector_type(4)));   // mfma accumulator

// LDS row stride for sX / sXl in u16 elements: 136*2 = 272 B -> row starts 16B-aligned.
#define XS 136

static __device__ __forceinline__ h2 pk(float a, float b) {
    return __builtin_bit_cast(h2, __builtin_amdgcn_cvt_pkrtz(a, b));
}
static __device__ __forceinline__ float dot2(h2 a, h2 b, float c) {
    return __builtin_amdgcn_fdot2(__builtin_bit_cast(hw2, a),
                                  __builtin_bit_cast(hw2, b), c, false);   // v_dot2_f32_f16
}
static __device__ __forceinline__ h2  b2h(u32 v) { return __builtin_bit_cast(h2, v); }
static __device__ __forceinline__ u32 h2u(h2 v)  { return __builtin_bit_cast(u32, v); }
static __device__ __forceinline__ h2  abs2(h2 v) { return b2h(h2u(v) & 0x7fff7fffu); }
static __device__ __forceinline__ u16 f2h(float f) { return __builtin_bit_cast(u16, (_Float16)f); }
static __device__ __forceinline__ float h2f(u16 v) { return (float)__builtin_bit_cast(_Float16, v); }
static __device__ __forceinline__ f4 mfma16(uint4 a, uint4 b, f4 c) {
    return __builtin_amdgcn_mfma_f32_16x16x32_f16(__builtin_bit_cast(hw8, a),
                                                  __builtin_bit_cast(hw8, b), c, 0, 0, 0);
}
static __device__ __forceinline__ h2 shflx32(h2 v) {
    return b2h((u32)__shfl_xor((int)h2u(v), 32));
}

// ---------------- K0: pack weights f32 -> MFMA B-fragment-ordered f16 ----------------
// wpk (u32): [0]=L1 [8192]=R1 [16384]=L2 [24576]=R2 [32768]=L3 [36864]=R3 ; 160 KB
__global__ void pack_weights(const float* __restrict__ Wl1, const float* __restrict__ Wr1,
                             const float* __restrict__ Wl2, const float* __restrict__ Wr2,
                             const float* __restrict__ Wl3, const float* __restrict__ Wr3,
                             u32* __restrict__ wpk)
{
    const int o = blockIdx.x * 256 + threadIdx.x;    // 0 .. 40959
    const float* src; u32* dst; int local; int N;
    if      (o < 8192)  { src = Wl1; dst = wpk;         local = o;         N = 128; }
    else if (o < 16384) { src = Wr1; dst = wpk + 8192;  local = o - 8192;  N = 128; }
    else if (o < 24576) { src = Wl2; dst = wpk + 16384; local = o - 16384; N = 128; }
    else if (o < 32768) { src = Wr2; dst = wpk + 24576; local = o - 24576; N = 128; }
    else if (o < 36864) { src = Wl3; dst = wpk + 32768; local = o - 32768; N = 64;  }
    else                { src = Wr3; dst = wpk + 36864; local = o - 36864; N = 64;  }
    const int i2   = local & 3;
    const int lane = (local >> 2) & 63;
    const int frag = local >> 8;
    const int kb   = frag & 3;
    const int nt   = frag >> 2;
    const int k0   = kb*32 + ((lane >> 4) << 3) + i2*2;
    const int n    = nt*16 + (lane & 15);
    dst[local] = h2u(pk(src[k0*N + n], src[(k0+1)*N + n]));
}

// ---------------- shared device pieces ----------------
static __device__ __forceinline__ void compute_imp(int t, int b,
    const float* __restrict__ team_mask, const float* __restrict__ ltm, float* sImp)
{
    if (t < 64) {
        float im;
        if (t < 16) im = (team_mask[b*32 + t] != -1000000000.0f) ? 1.f : 0.f;
        else        im = (ltm[b*49 + (t-16)] != 0.0f) ? 1.f : 0.f;
        sImp[t] = im;
    }
}

// full 128-col MFMA projection, A-frags from LDS sX (layer 1)
static __device__ __forceinline__ void matmul128(int w, int lane,
    const u32* __restrict__ wpkL, const u32* __restrict__ wpkR,
    const u16* sX, u16* sXl, uint4* sXrP)
{
    const int  mt  = w & 3;
    const bool isR = (w >= 4);
    const u32* wp  = isR ? wpkR : wpkL;
    const int  n15 = lane & 15;
    const int  qd  = lane >> 4;
    uint4 afr[4];
#pragma unroll
    for (int kb = 0; kb < 4; kb++)
        afr[kb] = *(const uint4*)&sX[(mt*16 + n15)*XS + kb*32 + (qd << 3)];
#pragma unroll
    for (int nt = 0; nt < 8; nt++) {
        f4 acc = {0.f, 0.f, 0.f, 0.f};
#pragma unroll
        for (int kb = 0; kb < 4; kb++) {
            uint4 bf = *(const uint4*)&wp[((nt*4 + kb)*64 + lane)*4];
            acc = mfma16(afr[kb], bf, acc);
        }
        const int n  = nt*16 + n15;
        const int mb = mt*16 + (qd << 2);
        if (!isR) {
#pragma unroll
            for (int r = 0; r < 4; r++) sXl[(mb + r)*XS + n] = f2h(acc[r]);
        } else {
            u16* xp = (u16*)sXrP;
#pragma unroll
            for (int r = 0; r < 4; r++)
                xp[(((n >> 3)*64) + mb + r)*8 + (n & 7)] = f2h(acc[r]);
        }
    }
}

// full 128-col MFMA projection, A-frags straight from global activation row (layers 2/3)
static __device__ __forceinline__ void matmul128g(int w, int lane,
    const u32* __restrict__ wpkL, const u32* __restrict__ wpkR,
    const u32* __restrict__ gxRow, u16* sXl, uint4* sXrP)
{
    const int  mt  = w & 3;
    const bool isR = (w >= 4);
    const u32* wp  = isR ? wpkR : wpkL;
    const int  n15 = lane & 15;
    const int  qd  = lane >> 4;
    const int  m   = mt*16 + n15;
    uint4 afr[4];
#pragma unroll
    for (int kb = 0; kb < 4; kb++)
        afr[kb] = *(const uint4*)&gxRow[m*64 + kb*16 + qd*4];
#pragma unroll
    for (int nt = 0; nt < 8; nt++) {
        f4 acc = {0.f, 0.f, 0.f, 0.f};
#pragma unroll
        for (int kb = 0; kb < 4; kb++) {
            uint4 bf = *(const uint4*)&wp[((nt*4 + kb)*64 + lane)*4];
            acc = mfma16(afr[kb], bf, acc);
        }
        const int n  = nt*16 + n15;
        const int mb = mt*16 + (qd << 2);
        if (!isR) {
#pragma unroll
            for (int r = 0; r < 4; r++) sXl[(mb + r)*XS + n] = f2h(acc[r]);
        } else {
            u16* xp = (u16*)sXrP;
#pragma unroll
            for (int r = 0; r < 4; r++)
                xp[(((n >> 3)*64) + mb + r)*8 + (n & 7)] = f2h(acc[r]);
        }
    }
}

// attention (H=4,C=32) + bias + LN + ReLU for this block's 32 dst nodes;
// direct coalesced-ish store of f16 activations to gxOut (u32 pairs).
static __device__ __forceinline__ void attn_ln(int t, int w, int lane, int b, int jh,
    const float* __restrict__ att, const float* __restrict__ bias,
    const float* __restrict__ lg, const float* __restrict__ lb,
    u16* sX, const u16* sXl, const uint4* sXrP,
    float* sAl, float* sPart, float* sL2, const float* sImp, u32* __restrict__ gxOut)
{
    const int h  = w & 3;
    const int ih = w >> 2;
    const int jj = lane & 31;
    const int is = lane >> 5;
    const int j  = jh*32 + jj;

    h2 a2[16];
#pragma unroll
    for (int q = 0; q < 16; q++) a2[q] = pk(att[h*32 + 2*q], att[h*32 + 2*q + 1]);

    // Al[h][i] for all 64 i — waves 0-3, i = lane
    if (w < 4) {
        const uint4* pr = (const uint4*)&sXl[lane*XS + h*32];
        float al = 0.f;
#pragma unroll
        for (int c4 = 0; c4 < 4; c4++) {
            uint4 v = pr[c4];
            al = dot2(b2h(v.x), a2[c4*4+0], al);
            al = dot2(b2h(v.y), a2[c4*4+1], al);
            al = dot2(b2h(v.z), a2[c4*4+2], al);
            al = dot2(b2h(v.w), a2[c4*4+3], al);
        }
        sAl[h*64 + lane] = al;
    }

    // xr_j from packed buffer
    h2 xr2[16];
#pragma unroll
    for (int s = 0; s < 4; s++) {
        uint4 v = sXrP[(h*4 + s)*64 + j];
        xr2[s*4+0] = b2h(v.x); xr2[s*4+1] = b2h(v.y);
        xr2[s*4+2] = b2h(v.z); xr2[s*4+3] = b2h(v.w);
    }
    float Ar = 0.f;
#pragma unroll
    for (int q = 0; q < 16; q++) Ar = dot2(a2[q], xr2[q], Ar);
    const float impj = sImp[j];
    __syncthreads();            // sAl ready

    // i-loop: 16 i's per thread (ih cross-wave split x is in-wave split)
    float l = 0.f;
    h2 acc2[16];
#pragma unroll
    for (int q = 0; q < 16; q++) acc2[q] = b2h(0u);
    const int i0 = ih*32 + is*16;
#pragma unroll 4
    for (int ii = 0; ii < 16; ii++) {
        int i = i0 + ii;
        const uint4* pl = (const uint4*)&sXl[i*XS + h*32];
        uint4 v0 = pl[0], v1 = pl[1], v2 = pl[2], v3 = pl[3];
        h2 xl2[16];
        xl2[0] = b2h(v0.x); xl2[1] = b2h(v0.y); xl2[2]  = b2h(v0.z); xl2[3]  = b2h(v0.w);
        xl2[4] = b2h(v1.x); xl2[5] = b2h(v1.y); xl2[6]  = b2h(v1.z); xl2[7]  = b2h(v1.w);
        xl2[8] = b2h(v2.x); xl2[9] = b2h(v2.y); xl2[10] = b2h(v2.z); xl2[11] = b2h(v2.w);
        xl2[12]= b2h(v3.x); xl2[13]= b2h(v3.y); xl2[14] = b2h(v3.z); xl2[15] = b2h(v3.w);
        float S0 = 0.f, S1 = 0.f;
#pragma unroll
        for (int q = 0; q < 16; q += 2) {
            h2 t0 = abs2(xl2[q]   + xr2[q]);
            h2 t1 = abs2(xl2[q+1] + xr2[q+1]);
            S0 = dot2(a2[q],   t0, S0);
            S1 = dot2(a2[q+1], t1, S1);
        }
        float e  = 0.6f*(sAl[h*64 + i] + Ar) + 0.4f*(S0 + S1);
        float ad = (i == j) ? 1.f : impj * sImp[i];
        float p  = (ad != 0.f) ? __expf(e) : 0.f;
        l += p;
        h2 p2 = pk(p, p);
#pragma unroll
        for (int q = 0; q < 16; q++) acc2[q] += p2 * xl2[q];
    }

    // in-wave combine (is halves)
    l += __shfl_xor(l, 32);
#pragma unroll
    for (int q = 0; q < 16; q++) acc2[q] = acc2[q] + shflx32(acc2[q]);

    // cross-wave (ih) combine via overlay on sX (x dead now); row stride 20 u32 (16B-aligned)
    u32* ov = (u32*)sX;
    if (w >= 4 && lane < 32) {
        uint4* d4 = (uint4*)(ov + (h*32 + jj)*20);
        uint4 o;
        o.x = h2u(acc2[0]);  o.y = h2u(acc2[1]);  o.z = h2u(acc2[2]);  o.w = h2u(acc2[3]);  d4[0] = o;
        o.x = h2u(acc2[4]);  o.y = h2u(acc2[5]);  o.z = h2u(acc2[6]);  o.w = h2u(acc2[7]);  d4[1] = o;
        o.x = h2u(acc2[8]);  o.y = h2u(acc2[9]);  o.z = h2u(acc2[10]); o.w = h2u(acc2[11]); d4[2] = o;
        o.x = h2u(acc2[12]); o.y = h2u(acc2[13]); o.z = h2u(acc2[14]); o.w = h2u(acc2[15]); d4[3] = o;
        sL2[h*32 + jj] = l;
    }
    __syncthreads();

    float yv[32];
    if (w < 4 && lane < 32) {
        const uint4* s4 = (const uint4*)(ov + (h*32 + jj)*20);
        uint4 u0 = s4[0], u1 = s4[1], u2 = s4[2], u3 = s4[3];
        h2 oth[16];
        oth[0] = b2h(u0.x); oth[1] = b2h(u0.y); oth[2]  = b2h(u0.z); oth[3]  = b2h(u0.w);
        oth[4] = b2h(u1.x); oth[5] = b2h(u1.y); oth[6]  = b2h(u1.z); oth[7]  = b2h(u1.w);
        oth[8] = b2h(u2.x); oth[9] = b2h(u2.y); oth[10] = b2h(u2.z); oth[11] = b2h(u2.w);
        oth[12]= b2h(u3.x); oth[13]= b2h(u3.y); oth[14] = b2h(u3.z); oth[15] = b2h(u3.w);
        l += sL2[h*32 + jj];
        const float rl = 1.f / l;
        float s1 = 0.f, s2v = 0.f;
#pragma unroll
        for (int q = 0; q < 16; q++) {
            h2 sum = acc2[q] + oth[q];
            float y0 = fmaf((float)sum[0], rl, bias[h*32 + 2*q]);
            float y1 = fmaf((float)sum[1], rl, bias[h*32 + 2*q + 1]);
            yv[2*q] = y0; yv[2*q+1] = y1;
            s1 += y0 + y1;
            s2v = fmaf(y0, y0, s2v);
            s2v = fmaf(y1, y1, s2v);
        }
        sPart[h*32 + jj]       = s1;
        sPart[128 + h*32 + jj] = s2v;
    }
    __syncthreads();

    if (w < 4 && lane < 32) {
        float su = sPart[jj] + sPart[32 + jj] + sPart[64 + jj] + sPart[96 + jj];
        float sq = sPart[128 + jj] + sPart[160 + jj] + sPart[192 + jj] + sPart[224 + jj];
        const float mean = su * 0.0078125f;
        const float var  = sq * 0.0078125f - mean*mean;
        const float rstd = rsqrtf(var + 1e-5f);
        u32 orow[16];
#pragma unroll
        for (int q = 0; q < 16; q++) {
            int f0 = h*32 + 2*q;
            float v0 = fmaxf(fmaf((yv[2*q]   - mean)*rstd, lg[f0],   lb[f0]),   0.f);
            float v1 = fmaxf(fmaf((yv[2*q+1] - mean)*rstd, lg[f0+1], lb[f0+1]), 0.f);
            orow[q] = h2u(pk(v0, v1));
        }
        // direct store: node j, u32 channel-pairs h*16 .. h*16+15 (16B-aligned)
        uint4* po = (uint4*)(gxOut + (size_t)b*4096 + (size_t)j*64 + h*16);
        po[0] = *(uint4*)&orow[0];
        po[1] = *(uint4*)&orow[4];
        po[2] = *(uint4*)&orow[8];
        po[3] = *(uint4*)&orow[12];
    }
}

// ---------------- kernel 1: embed + GAT layer 1 ----------------
__global__ void __launch_bounds__(512, 1) gnn_layer1(
    const float* __restrict__ team_obs, const float* __restrict__ target_obs,
    const float* __restrict__ team_mask, const float* __restrict__ ltm,
    const float* __restrict__ W_emb, const float* __restrict__ b_emb,
    const float* __restrict__ att1, const float* __restrict__ b1,
    const float* __restrict__ ln1_g, const float* __restrict__ ln1_b,
    const u32* __restrict__ wpk, u32* __restrict__ gx1)
{
    __shared__ __align__(16) u16   sX  [64*XS];
    __shared__ __align__(16) u16   sXl [64*XS];
    __shared__ __align__(16) uint4 sXrP[1024];
    __shared__ float sFin[1024];
    __shared__ float sAl [256];
    __shared__ float sPart[256];
    __shared__ float sL2 [128];
    __shared__ float sImp[64];

    const int t    = threadIdx.x;
    const int w    = t >> 6;
    const int lane = t & 63;
    const int b    = blockIdx.x & 127;   // XCD-pair swizzle: (b) and (b+128) share an XCD
    const int jh   = blockIdx.x >> 7;

    compute_imp(t, b, team_mask, ltm, sImp);
    for (int ee = t; ee < 1024; ee += 512) {
        int m = ee >> 4, k = ee & 15;
        float v = 0.f;
        if (m < 16) {
            if (k < 14) v = team_obs[(b*16 + m)*14 + k];
        } else {
            const float* tg = target_obs + (size_t)(b*48 + (m-16))*15;
            if      (k < 12)  v = tg[k];
            else if (k == 14) v = tg[12];
            else if (k == 15) v = tg[13];
        }
        sFin[m*16 + k] = v;
    }
    __syncthreads();

    // embed: x = fin @ W_emb + b_emb -> sX (f16)
    {
        const int f = t & 127;
        const int g = t >> 7;
        float wreg[16];
#pragma unroll
        for (int k = 0; k < 16; k++) wreg[k] = W_emb[k*128 + f];
        const float bf = b_emb[f];
#pragma unroll
        for (int mm = 0; mm < 16; mm++) {
            int m = g*16 + mm;
            const float4* pf = (const float4*)&sFin[m*16];
            float4 f0 = pf[0], f1 = pf[1], f2 = pf[2], f3 = pf[3];
            float acc = bf;
            acc = fmaf(f0.x, wreg[0],  acc); acc = fmaf(f0.y, wreg[1],  acc);
            acc = fmaf(f0.z, wreg[2],  acc); acc = fmaf(f0.w, wreg[3],  acc);
            acc = fmaf(f1.x, wreg[4],  acc); acc = fmaf(f1.y, wreg[5],  acc);
            acc = fmaf(f1.z, wreg[6],  acc); acc = fmaf(f1.w, wreg[7],  acc);
            acc = fmaf(f2.x, wreg[8],  acc); acc = fmaf(f2.y, wreg[9],  acc);
            acc = fmaf(f2.z, wreg[10], acc); acc = fmaf(f2.w, wreg[11], acc);
            acc = fmaf(f3.x, wreg[12], acc); acc = fmaf(f3.y, wreg[13], acc);
            acc = fmaf(f3.z, wreg[14], acc); acc = fmaf(f3.w, wreg[15], acc);
            sX[m*XS + f] = f2h(acc);
        }
    }
    __syncthreads();

    matmul128(w, lane, wpk, wpk + 8192, sX, sXl, sXrP);
    __syncthreads();
    attn_ln(t, w, lane, b, jh, att1, b1, ln1_g, ln1_b,
            sX, sXl, sXrP, sAl, sPart, sL2, sImp, gx1);
}

// ---------------- kernel 2: GAT layer 2 (A-frags straight from gx1) ----------------
__global__ void __launch_bounds__(512, 1) gnn_layer2(
    const float* __restrict__ team_mask, const float* __restrict__ ltm,
    const float* __restrict__ att2, const float* __restrict__ b2,
    const float* __restrict__ ln2_g, const float* __restrict__ ln2_b,
    const u32* __restrict__ wpk, const u32* __restrict__ gxIn, u32* __restrict__ gxOut)
{
    __shared__ __align__(16) u16   sX  [64*XS];   // overlay scratch only
    __shared__ __align__(16) u16   sXl [64*XS];
    __shared__ __align__(16) uint4 sXrP[1024];
    __shared__ float sAl [256];
    __shared__ float sPart[256];
    __shared__ float sL2 [128];
    __shared__ float sImp[64];

    const int t    = threadIdx.x;
    const int w    = t >> 6;
    const int lane = t & 63;
    const int b    = blockIdx.x & 127;
    const int jh   = blockIdx.x >> 7;

    compute_imp(t, b, team_mask, ltm, sImp);
    matmul128g(w, lane, wpk + 16384, wpk + 24576, gxIn + (size_t)b*4096, sXl, sXrP);
    __syncthreads();
    attn_ln(t, w, lane, b, jh, att2, b2, ln2_g, ln2_b,
            sX, sXl, sXrP, sAl, sPart, sL2, sImp, gxOut);
}

// ---------------- kernel 3: GAT layer 3 (H=1, C=64) + output ----------------
__global__ void __launch_bounds__(512, 1) gnn_layer3(
    const float* __restrict__ team_mask, const float* __restrict__ ltm,
    const float* __restrict__ att3, const float* __restrict__ b3,
    const u32* __restrict__ wpk, const u32* __restrict__ gxIn, float* __restrict__ out)
{
    __shared__ __align__(16) u16   sXl [64*XS];
    __shared__ __align__(16) uint4 sXrP[512];
    __shared__ float sAl [64];
    __shared__ float sPart[512];
    __shared__ float sImp[64];
    __shared__ u16   sE  [64*32];

    const int t    = threadIdx.x;
    const int w    = t >> 6;
    const int lane = t & 63;
    const int b    = blockIdx.x & 127;
    const int jh   = blockIdx.x >> 7;

    compute_imp(t, b, team_mask, ltm, sImp);
    const u32* gxRow = gxIn + (size_t)b*4096;

    // layer-3 MFMA matmul (HC = 64), A-frags from global
    {
        const int  mt  = w & 3;
        const bool isR = (w >= 4);
        const u32* wp  = isR ? (wpk + 36864) : (wpk + 32768);
        const int  n15 = lane & 15;
        const int  qd  = lane >> 4;
        const int  m   = mt*16 + n15;
        uint4 afr[4];
#pragma unroll
        for (int kb = 0; kb < 4; kb++)
            afr[kb] = *(const uint4*)&gxRow[m*64 + kb*16 + qd*4];
#pragma unroll
        for (int nt = 0; nt < 4; nt++) {
            f4 acc = {0.f, 0.f, 0.f, 0.f};
#pragma unroll
            for (int kb = 0; kb < 4; kb++) {
                uint4 bf = *(const uint4*)&wp[((nt*4 + kb)*64 + lane)*4];
                acc = mfma16(afr[kb], bf, acc);
            }
            const int n  = nt*16 + n15;
            const int mb = mt*16 + (qd << 2);
            if (!isR) {
#pragma unroll
                for (int r = 0; r < 4; r++) sXl[(mb + r)*XS + n] = f2h(acc[r]);
            } else {
                u16* xp = (u16*)sXrP;
#pragma unroll
                for (int r = 0; r < 4; r++)
                    xp[(((n >> 3)*64) + mb + r)*8 + (n & 7)] = f2h(acc[r]);
            }
        }
    }
    __syncthreads();

    // Al3[i] (8-way c-split)
    {
        h2 a2l[4];
#pragma unroll
        for (int q = 0; q < 4; q++) a2l[q] = pk(att3[w*8 + 2*q], att3[w*8 + 2*q + 1]);
        uint4 v = *(const uint4*)&sXl[lane*XS + w*8];
        float al = 0.f;
        al = dot2(b2h(v.x), a2l[0], al);
        al = dot2(b2h(v.y), a2l[1], al);
        al = dot2(b2h(v.z), a2l[2], al);
        al = dot2(b2h(v.w), a2l[3], al);
        sPart[w*64 + lane] = al;
    }
    __syncthreads();
    if (t < 64) {
        sAl[t] = ((sPart[t] + sPart[64+t]) + (sPart[128+t] + sPart[192+t]))
               + ((sPart[256+t] + sPart[320+t]) + (sPart[384+t] + sPart[448+t]));
    }
    __syncthreads();

    const int jj = lane & 31;
    const int is = lane >> 5;
    const int j  = jh*32 + jj;

    // scores e[i][jj]; i split 16 ways (8 waves x 2 in-wave)
    {
        h2 a3[32], xr3[32];
#pragma unroll
        for (int q = 0; q < 32; q++) a3[q] = pk(att3[2*q], att3[2*q + 1]);
#pragma unroll
        for (int s = 0; s < 8; s++) {
            uint4 v = sXrP[s*64 + j];
            xr3[s*4+0] = b2h(v.x); xr3[s*4+1] = b2h(v.y);
            xr3[s*4+2] = b2h(v.z); xr3[s*4+3] = b2h(v.w);
        }
        float Ar = 0.f;
#pragma unroll
        for (int q = 0; q < 32; q++) Ar = dot2(a3[q], xr3[q], Ar);
        const float impj = sImp[j];
        const int ib = (w*2 + is)*4;
        for (int ii = 0; ii < 4; ii++) {
            int i = ib + ii;
            const uint4* pl = (const uint4*)&sXl[i*XS];
            float S0 = 0.f, S1 = 0.f;
#pragma unroll
            for (int c4 = 0; c4 < 8; c4++) {
                uint4 v = pl[c4];
                S0 = dot2(a3[c4*4+0], abs2(b2h(v.x) + xr3[c4*4+0]), S0);
                S1 = dot2(a3[c4*4+1], abs2(b2h(v.y) + xr3[c4*4+1]), S1);
                S0 = dot2(a3[c4*4+2], abs2(b2h(v.z) + xr3[c4*4+2]), S0);
                S1 = dot2(a3[c4*4+3], abs2(b2h(v.w) + xr3[c4*4+3]), S1);
            }
            float e  = 0.6f*(sAl[i] + Ar) + 0.4f*(S0 + S1);
            float ad = (i == j) ? 1.f : impj * sImp[i];
            e = (ad != 0.f) ? e : -60000.0f;
            sE[i*32 + jj] = f2h(e);
        }
    }
    __syncthreads();

    // softmax + aggregate (c split 8 ways, i split 2 in-wave)
    {
        const int c0 = w*8;
        h2 acc2[4];
#pragma unroll
        for (int q = 0; q < 4; q++) acc2[q] = b2h(0u);
        float l = 0.f;
        for (int k = 0; k < 32; k++) {
            int i = is*32 + k;
            float p = __expf(h2f(sE[i*32 + jj]));
            l += p;
            h2 p2 = pk(p, p);
            uint4 v = *(const uint4*)&sXl[i*XS + c0];
            acc2[0] += p2 * b2h(v.x);
            acc2[1] += p2 * b2h(v.y);
            acc2[2] += p2 * b2h(v.z);
            acc2[3] += p2 * b2h(v.w);
        }
        l += __shfl_xor(l, 32);
#pragma unroll
        for (int q = 0; q < 4; q++) acc2[q] = acc2[q] + shflx32(acc2[q]);
        if (is == 0) {
            const float rl = 1.f / l;
            float o[8];
#pragma unroll
            for (int q = 0; q < 4; q++) {
                o[2*q]   = fmaf((float)acc2[q][0], rl, b3[c0 + 2*q]);
                o[2*q+1] = fmaf((float)acc2[q][1], rl, b3[c0 + 2*q + 1]);
            }
            float4* po = (float4*)(out + (size_t)b*4096 + (size_t)j*64 + c0);
            po[0] = *(const float4*)&o[0];
            po[1] = *(const float4*)&o[4];
        }
    }
}

extern "C" void kernel_launch(void* const* d_in, const int* in_sizes, int n_in,
                              void* d_out, int out_size, void* d_ws, size_t ws_size,
                              hipStream_t stream) {
    (void)in_sizes; (void)n_in; (void)ws_size; (void)out_size;
    const float* team_obs          = (const float*)d_in[0];
    const float* target_obs        = (const float*)d_in[1];
    const float* team_mask         = (const float*)d_in[2];
    const float* local_target_mask = (const float*)d_in[3];
    const float* W_emb             = (const float*)d_in[4];
    const float* b_emb             = (const float*)d_in[5];
    const float* Wl1               = (const float*)d_in[6];
    const float* Wr1               = (const float*)d_in[7];
    const float* att1              = (const float*)d_in[8];
    const float* b1                = (const float*)d_in[9];
    const float* Wl2               = (const float*)d_in[10];
    const float* Wr2               = (const float*)d_in[11];
    const float* att2              = (const float*)d_in[12];
    const float* b2                = (const float*)d_in[13];
    const float* Wl3               = (const float*)d_in[14];
    const float* Wr3               = (const float*)d_in[15];
    const float* att3              = (const float*)d_in[16];
    const float* b3                = (const float*)d_in[17];
    const float* ln1_g             = (const float*)d_in[18];
    const float* ln1_b             = (const float*)d_in[19];
    const float* ln2_g             = (const float*)d_in[20];
    const float* ln2_b             = (const float*)d_in[21];
    float* out = (float*)d_out;

    u32* wpk = (u32*)d_ws;                 // 163840 B
    u32* gx2 = (u32*)d_ws + 40960;         // 2 MB interlayer activations (layer2 out)
    u32* gx1 = (u32*)d_out;                // d_out reused as layer1-out scratch (2 MB exact)

    pack_weights<<<dim3(160), dim3(256), 0, stream>>>(Wl1, Wr1, Wl2, Wr2, Wl3, Wr3, wpk);
    gnn_layer1<<<dim3(256), dim3(512), 0, stream>>>(
        team_obs, target_obs, team_mask, local_target_mask, W_emb, b_emb,
        att1, b1, ln1_g, ln1_b, wpk, gx1);
    gnn_layer2<<<dim3(256), dim3(512), 0, stream>>>(
        team_mask, local_target_mask, att2, b2, ln2_g, ln2_b, wpk, gx1, gx2);
    gnn_layer3<<<dim3(256), dim3(512), 0, stream>>>(
        team_mask, local_target_mask, att3, b3, wpk, gx2, out);
}